// Round 12
// baseline (2148.768 us; speedup 1.0000x reference)
//
#include <hip/hip_runtime.h>
#include <hip/hip_bf16.h>

// ---------------------------------------------------------------------------
// Round 12: DOUBLE PROBE. R11 design unchanged; gemm x32 and attn x32 serial
// reps (opaque zero dep) so both appear in rocprof top-5 with real counters.
// prep/final x1. All reps idempotent -> output identical to R11.
// ---------------------------------------------------------------------------

#define NNODES 192
#define CFEAT  2048

typedef __attribute__((ext_vector_type(8))) short bf16x8;
typedef __attribute__((ext_vector_type(4))) float f32x4;

__device__ inline unsigned f2bf(float f) {                 // RNE f32 -> bf16
    union { float f; unsigned u; } v; v.f = f;
    unsigned u = v.u;
    u += 0x7FFFu + ((u >> 16) & 1u);
    return u >> 16;
}

// ---- pool body (measured R7: ~33.5us at BW floor)
__device__ inline void pool_body(int bid, int tid, const float* __restrict__ F,
                                 float* __restrict__ POOL,
                                 unsigned short* __restrict__ POOLB) {
    int wave = tid >> 6, lane = tid & 63;
    #pragma unroll
    for (int it = 0; it < 12; ++it) {
        int dr = bid * 4 + wave + it * 16384;          // [0, 196608)
        int r0 = dr * 2;
        int n = r0 >> 11, c0 = r0 & 2047;
        int p = n >> 5, b = n & 31;                    // n = p*32 + b
        const float* src = F + (((size_t)b * 12288 + (size_t)p * 2048 + c0) << 7);
        float4 v = *(const float4*)(src + (lane << 2));
        float acc = (v.x + v.y) + (v.z + v.w);
        acc += __shfl_down(acc, 16);
        acc += __shfl_down(acc, 8);
        acc += __shfl_down(acc, 4);
        acc += __shfl_down(acc, 2);
        acc += __shfl_down(acc, 1);
        if ((lane & 31) == 0) {
            int r = r0 + (lane >> 5);
            float m = acc * (1.0f / 128.0f);
            POOL[r] = m;
            POOLB[r] = (unsigned short)f2bf(m);
        }
    }
}

// ---- wtrans body (proven R10)
__device__ inline void wtrans_body(int bid2, int tid, unsigned short* tt,
                                   const float* __restrict__ WL,
                                   const float* __restrict__ WR,
                                   unsigned short* __restrict__ WT) {
    int nt = bid2 & 7;
    int kt = (bid2 >> 3) & 31;
    int h  = (bid2 >> 8) & 3;
    int s  = bid2 >> 10;
    const float* src = (s ? WR : WL) + (size_t)h * (2048 * 512)
                     + (size_t)(kt * 64) * 512 + nt * 64;
    int nf = tid & 15, kr = tid >> 4;
    #pragma unroll
    for (int p = 0; p < 4; ++p) {
        int k = kr + p * 16;
        float4 v = *(const float4*)(src + (size_t)k * 512 + nf * 4);
        tt[(nf * 4 + 0) * 74 + k] = (unsigned short)f2bf(v.x);
        tt[(nf * 4 + 1) * 74 + k] = (unsigned short)f2bf(v.y);
        tt[(nf * 4 + 2) * 74 + k] = (unsigned short)f2bf(v.z);
        tt[(nf * 4 + 3) * 74 + k] = (unsigned short)f2bf(v.w);
    }
    __syncthreads();
    int kc = (tid & 7) * 8, nr = tid >> 3;
    size_t base = ((size_t)(s * 2048 + h * 512 + nt * 64)) * 2048 + kt * 64;
    #pragma unroll
    for (int p = 0; p < 2; ++p) {
        int n = nr + p * 32;
        const unsigned short* rp = tt + n * 74 + kc;
        uint4 o;
        o.x = *(const unsigned*)(rp + 0);
        o.y = *(const unsigned*)(rp + 2);
        o.z = *(const unsigned*)(rp + 4);
        o.w = *(const unsigned*)(rp + 6);
        *(uint4*)(WT + base + (size_t)n * 2048 + kc) = o;
    }
}

// ---- 1a. Fused prep: blocks [0,4096) pool; [4096,8192) wtrans L0/L1
__global__ __launch_bounds__(256) void prep_kernel(
    const float* __restrict__ F, float* __restrict__ POOL,
    unsigned short* __restrict__ POOLB,
    const float* __restrict__ Wl, const float* __restrict__ Wr,
    unsigned short* __restrict__ WT) {
    __shared__ unsigned short tt[64 * 74];
    int bid = blockIdx.x, tid = threadIdx.x;
    if (bid < 4096) {
        pool_body(bid, tid, F, POOL, POOLB);
    } else {
        int local = bid - 4096;
        int lyr = local >> 11, bid2 = local & 2047;
        const size_t WOFF = 4ull * 2048 * 512;
        wtrans_body(bid2, tid, tt, Wl + lyr * WOFF, Wr + lyr * WOFF,
                    WT + (size_t)lyr * (4096ull * 2048));
    }
}

// ---- 1b/1c. standalone fallbacks
__global__ __launch_bounds__(256) void pool_kernel(
    const float* __restrict__ F, float* __restrict__ POOL,
    unsigned short* __restrict__ POOLB) {
    pool_body(blockIdx.x, threadIdx.x, F, POOL, POOLB);
}
__global__ __launch_bounds__(256) void wtrans_kernel(
    const float* __restrict__ WL, const float* __restrict__ WR,
    unsigned short* __restrict__ WT) {
    __shared__ unsigned short tt[64 * 74];
    wtrans_body(blockIdx.x, threadIdx.x, tt, WL, WR, WT);
}

// ---- 2. GEMM v5 (x32 probe reps): Y[192][4096] = X @ WT^T + bias.
__global__ __launch_bounds__(512) void gemm_kernel(
    const unsigned short* __restrict__ X,    // bf16 [192][2048]
    const unsigned short* __restrict__ WT,   // bf16 [4096][2048] (layer slice)
    const float* __restrict__ BL,
    const float* __restrict__ BR,
    float* __restrict__ Y) {                 // fp32 [192][4096]
    __shared__ float red[8 * 192 * 18];

    int ct = blockIdx.x;                     // [0,256)
    int t = threadIdx.x, w = t >> 6, l = t & 63;
    int lr = l & 15, lg = l >> 4;

    int ncol = ct << 4;
    bool sideR = ncol >= 2048;
    const float* Bb = (sideR ? BR : BL) + (ncol & 2047);
    int kw = w << 8;

    int dep = 0;
    #pragma unroll 1
    for (int rep = 0; rep < 32; ++rep) {
        __syncthreads();                     // protect red[] across reps
        const unsigned short* Wp = WT + (size_t)(ncol + lr) * 2048 + kw + lg * 8 + dep;
        const unsigned short* Xp = X + (size_t)lr * 2048 + kw + lg * 8 + dep;

        bf16x8 bfr0 = *(const bf16x8*)(Wp + 0 * 32);
        bf16x8 bfr1 = *(const bf16x8*)(Wp + 1 * 32);
        bf16x8 bfr2 = *(const bf16x8*)(Wp + 2 * 32);
        bf16x8 bfr3 = *(const bf16x8*)(Wp + 3 * 32);
        bf16x8 bfr4 = *(const bf16x8*)(Wp + 4 * 32);
        bf16x8 bfr5 = *(const bf16x8*)(Wp + 5 * 32);
        bf16x8 bfr6 = *(const bf16x8*)(Wp + 6 * 32);
        bf16x8 bfr7 = *(const bf16x8*)(Wp + 7 * 32);

        f32x4 acc[12];
        #pragma unroll
        for (int fi = 0; fi < 12; ++fi) acc[fi] = {0.f, 0.f, 0.f, 0.f};

#define KSTEP(s, bfr)                                                         \
        {                                                                     \
            _Pragma("unroll")                                                 \
            for (int fi = 0; fi < 12; ++fi) {                                 \
                bf16x8 af = *(const bf16x8*)(Xp + (size_t)fi * 16 * 2048 + (s) * 32); \
                acc[fi] = __builtin_amdgcn_mfma_f32_16x16x32_bf16(            \
                              af, bfr, acc[fi], 0, 0, 0);                     \
            }                                                                 \
        }
        KSTEP(0, bfr0) KSTEP(1, bfr1) KSTEP(2, bfr2) KSTEP(3, bfr3)
        KSTEP(4, bfr4) KSTEP(5, bfr5) KSTEP(6, bfr6) KSTEP(7, bfr7)
#undef KSTEP

        #pragma unroll
        for (int fi = 0; fi < 12; ++fi)
            #pragma unroll
            for (int j = 0; j < 4; ++j)
                red[(w * 192 + fi * 16 + lg * 4 + j) * 18 + lr] = acc[fi][j];
        __syncthreads();

        #pragma unroll
        for (int e = 0; e < 6; ++e) {
            int idx = t + e * 512;
            int row = idx >> 4, col = idx & 15;
            float sum = 0.f;
            #pragma unroll
            for (int ww = 0; ww < 8; ++ww)
                sum += red[(ww * 192 + row) * 18 + col];
            Y[(size_t)row * 4096 + ncol + col] = sum + Bb[col];
        }
        dep = (acc[0][0] > 1e30f) ? 1 : 0;   // always 0, opaque serializer
    }
}

// ---- 3. Attention (x32 probe reps) per (instance g, head h).
template <int LAYER>
__global__ __launch_bounds__(256) void attn_kernel(
    const float* __restrict__ Y,
    const float* __restrict__ ATT,
    const float* __restrict__ GBIAS,
    const int* __restrict__ NPS,
    const float* __restrict__ POOL,
    float* __restrict__ OUTF,
    unsigned short* __restrict__ OUTB) {
    __shared__ float xls[6][512];
    __shared__ float xrs[6][512];
    __shared__ float atts[512];
    __shared__ float s_sm[6][6];
    __shared__ float alpha[6][6];

    int g = blockIdx.x, h = blockIdx.y;
    int tid = threadIdx.x;
    int cnt = NPS[g];

    int dep = 0;
    #pragma unroll 1
    for (int rep = 0; rep < 32; ++rep) {
        __syncthreads();                     // protect LDS across reps
        for (int idx = tid; idx < 6 * 512; idx += 256) {
            int q = idx >> 9, d = idx & 511;
            size_t off = (size_t)(g * 6 + q) * 4096 + h * 512 + d + dep;
            xls[q][d] = Y[off];
            xrs[q][d] = Y[off + 2048];
        }
        for (int d = tid; d < 512; d += 256) atts[d] = ATT[h * 512 + d];
        __syncthreads();

        int wv = tid >> 6, lane = tid & 63;
        for (int p = wv; p < 36; p += 4) {
            int i = p / 6, j = p % 6;
            float acc = 0.f;
            #pragma unroll
            for (int u = 0; u < 8; ++u) {
                int d = lane + u * 64;
                float v = xrs[i][d] + xls[j][d];
                v = (v >= 0.f) ? v : 0.2f * v;
                acc = fmaf(atts[d], v, acc);
            }
            #pragma unroll
            for (int off = 32; off; off >>= 1) acc += __shfl_down(acc, off);
            if (lane == 0) s_sm[i][j] = acc;
        }
        __syncthreads();

        if (tid < 6) {
            int i = tid;
            bool iv = i < cnt;
            float mx;
            if (iv) {
                mx = -1e30f;
                for (int j = 0; j < cnt; ++j) mx = fmaxf(mx, s_sm[i][j]);
            } else {
                mx = s_sm[i][i];
            }
            float e[6], sum = 0.f;
            for (int j = 0; j < 6; ++j) {
                bool nb = iv ? (j < cnt) : (j == i);
                e[j] = nb ? expf(s_sm[i][j] - mx) : 0.f;
                sum += e[j];
            }
            float inv = 1.f / sum;
            for (int j = 0; j < 6; ++j) alpha[i][j] = e[j] * inv;
        }
        __syncthreads();

        float probe = 0.f;
        for (int idx = tid; idx < 6 * 512; idx += 256) {
            int q = idx >> 9, d = idx & 511;
            float acc = 0.f;
            #pragma unroll
            for (int j = 0; j < 6; ++j) acc = fmaf(alpha[q][j], xls[j][d], acc);
            int col = h * 512 + d;
            size_t off = (size_t)(g * 6 + q) * 2048 + col;
            float v = acc + GBIAS[col];
            if (LAYER == 0) {
                v = (v > 0.f) ? v : expm1f(v);
                OUTB[off] = (unsigned short)f2bf(v);
            } else {
                v = v + POOL[off];
                OUTF[off] = v;
            }
            probe += v;
        }
        dep = (probe > 1e30f) ? 1 : 0;       // always 0, opaque serializer
    }
}

// ---- 4. Part-mean + BN
__global__ __launch_bounds__(256) void final_kernel(
    const float* __restrict__ GF, const float* __restrict__ GAMMA,
    const float* __restrict__ MEAN, const float* __restrict__ VAR,
    float* __restrict__ OUTP) {
    int idx = blockIdx.x * 256 + threadIdx.x;   // [0, 65536)
    int c = idx & 2047, b = idx >> 11;
    float acc = 0.f;
    #pragma unroll
    for (int p = 0; p < 6; ++p) acc += GF[(size_t)(p * 32 + b) * 2048 + c];
    acc *= (1.f / 6.f);
    OUTP[idx] = GAMMA[c] * (acc - MEAN[c]) * rsqrtf(VAR[c] + 1e-5f);
}

extern "C" void kernel_launch(void* const* d_in, const int* in_sizes, int n_in,
                              void* d_out, int out_size, void* d_ws, size_t ws_size,
                              hipStream_t stream) {
    const float* F     = (const float*)d_in[0];
    const int*   nps   = (const int*)d_in[1];
    const float* Wl    = (const float*)d_in[2];
    const float* bl    = (const float*)d_in[3];
    const float* Wr    = (const float*)d_in[4];
    const float* br    = (const float*)d_in[5];
    const float* att   = (const float*)d_in[6];
    const float* gb    = (const float*)d_in[7];
    const float* gamma = (const float*)d_in[8];
    const float* mean  = (const float*)d_in[9];
    const float* var   = (const float*)d_in[10];
    float* out = (float*)d_out;
    float* wsf = (float*)d_ws;

    const size_t SZ = (size_t)NNODES * CFEAT;        // 393216 floats
    const size_t WT_ELEMS = 4096ull * 2048;

    float* pool = wsf;
    float* gf   = wsf + SZ;
    float* Y    = wsf + 2 * SZ;
    unsigned short* poolb = (unsigned short*)(wsf + 4 * SZ);
    unsigned short* x1b   = (unsigned short*)(wsf + 5 * SZ);
    unsigned short* WT    = (unsigned short*)(wsf + 6 * SZ);

    const size_t WOFF = 4ull * 2048 * 512;
    size_t need_fused = 6 * SZ * 4 + 2 * WT_ELEMS * 2;

    if (ws_size >= need_fused) {
        prep_kernel<<<dim3(8192), dim3(256), 0, stream>>>(F, pool, poolb,
                                                          Wl, Wr, WT);
        gemm_kernel<<<dim3(256), dim3(512), 0, stream>>>(poolb, WT, bl, br, Y);
        attn_kernel<0><<<dim3(32, 4), dim3(256), 0, stream>>>(Y, att, gb, nps,
                                                              nullptr, nullptr, x1b);
        gemm_kernel<<<dim3(256), dim3(512), 0, stream>>>(x1b, WT + WT_ELEMS,
                                                         bl + 2048, br + 2048, Y);
        attn_kernel<1><<<dim3(32, 4), dim3(256), 0, stream>>>(Y, att + 2048,
                                                              gb + 2048, nps,
                                                              pool, gf, nullptr);
    } else {
        pool_kernel<<<dim3(4096), dim3(256), 0, stream>>>(F, pool, poolb);
        wtrans_kernel<<<dim3(2048), dim3(256), 0, stream>>>(Wl, Wr, WT);
        gemm_kernel<<<dim3(256), dim3(512), 0, stream>>>(poolb, WT, bl, br, Y);
        attn_kernel<0><<<dim3(32, 4), dim3(256), 0, stream>>>(Y, att, gb, nps,
                                                              nullptr, nullptr, x1b);
        wtrans_kernel<<<dim3(2048), dim3(256), 0, stream>>>(Wl + WOFF, Wr + WOFF, WT);
        gemm_kernel<<<dim3(256), dim3(512), 0, stream>>>(x1b, WT,
                                                         bl + 2048, br + 2048, Y);
        attn_kernel<1><<<dim3(32, 4), dim3(256), 0, stream>>>(Y, att + 2048,
                                                              gb + 2048, nps,
                                                              pool, gf, nullptr);
    }

    final_kernel<<<dim3(256), dim3(256), 0, stream>>>(gf, gamma, mean, var, out);
}